// Round 1
// baseline (526.439 us; speedup 1.0000x reference)
//
#include <hip/hip_runtime.h>
#include <stdint.h>

// ---------------------------------------------------------------------------
// CrossAttention2D on MI355X (gfx950)
// B=4, C=D=256, H=W=64, N=4096. fp32 in/out.
// Strategy: split-bf16 (hi/lo) 3-term MFMA everywhere (~1e-4 rel accuracy),
// flash attention with swapped QK^T, 128KB double-buffered LDS staging via
// global_load_lds with source-side XOR chunk swizzle, fused output projection.
// ---------------------------------------------------------------------------

#define NB 4
#define CC 256
#define DD 256
#define NN 4096
#define PS (NB * NN * DD)   // elements per bf16 plane (4,194,304)

typedef float f32x4 __attribute__((ext_vector_type(4)));
typedef unsigned int u32x4 __attribute__((ext_vector_type(4)));
typedef __bf16 bf16x8 __attribute__((ext_vector_type(8)));

#define MFMA16(a, b, c) __builtin_amdgcn_mfma_f32_16x16x32_bf16((a), (b), (c), 0, 0, 0)

__device__ __forceinline__ uint32_t bf16rne(float x) {
    uint32_t u = __float_as_uint(x);
    return (u + 0x7fffu + ((u >> 16) & 1u)) >> 16;
}
__device__ __forceinline__ float bf16tof(uint32_t h) { return __uint_as_float(h << 16); }

// split 8 fp32 values into hi/lo bf16x8 fragments (element j = k-index j)
__device__ __forceinline__ void split8(const float* v, bf16x8& hi, bf16x8& lo) {
    u32x4 hw, lw;
#pragma unroll
    for (int w = 0; w < 4; ++w) {
        float x = v[2 * w], y = v[2 * w + 1];
        uint32_t hx = bf16rne(x), hy = bf16rne(y);
        uint32_t lx = bf16rne(x - bf16tof(hx)), ly = bf16rne(y - bf16tof(hy));
        hw[w] = hx | (hy << 16);
        lw[w] = lx | (ly << 16);
    }
    hi = __builtin_bit_cast(bf16x8, hw);
    lo = __builtin_bit_cast(bf16x8, lw);
}

__device__ __forceinline__ bf16x8 ldsld8(const void* p) {
    return __builtin_bit_cast(bf16x8, *(const u32x4*)p);
}

// ---------------------------------------------------------------------------
// Kernel 1: QKV projections + bias + positional encoding + split to bf16 planes
//   proj 0: Q = (Wq*Y + bq + pe) * 1/16   -> Qh/Ql [B][N][D]
//   proj 1: K =  Wk*S + bk + pe           -> Kh/Kl [B][N][D]
//   proj 2: V =  Wv*S + bv                -> Vh/Vl [B][D][N]  (d-major)
// grid = 3*4*4*64 = 3072 blocks of 256 threads; 64x64 output tile each.
// ---------------------------------------------------------------------------
__global__ __launch_bounds__(256) void proj_kernel(
    const float* __restrict__ Y, const float* __restrict__ S,
    const float* __restrict__ Wq, const float* __restrict__ bq,
    const float* __restrict__ Wk, const float* __restrict__ bk,
    const float* __restrict__ Wv, const float* __restrict__ bv,
    uint16_t* __restrict__ Qh, uint16_t* __restrict__ Ql,
    uint16_t* __restrict__ Kh, uint16_t* __restrict__ Kl,
    uint16_t* __restrict__ Vh, uint16_t* __restrict__ Vl) {
    __shared__ float Xs[32 * 66];  // staged X tile [c=32][n=64] pad->66
    __shared__ float Bz[64 * 68];  // transpose bounce [n=64][d=64] pad->68

    int bi = blockIdx.x;
    int proj = bi >> 10;
    int rem = bi & 1023;
    int b = rem >> 8;
    int dt = (rem >> 6) & 3;
    int nt = rem & 63;
    int d0 = dt * 64, n0 = nt * 64;

    int t = threadIdx.x;
    int lane = t & 63, wv = t >> 6;
    int g = lane >> 4, li = lane & 15;

    const float* X = (proj == 0 ? Y : S) + (size_t)b * CC * NN;
    const float* W = proj == 0 ? Wq : (proj == 1 ? Wk : Wv);
    const float* bias = proj == 0 ? bq : (proj == 1 ? bk : bv);

    f32x4 acc[4];
#pragma unroll
    for (int i = 0; i < 4; ++i) acc[i] = (f32x4){0.f, 0.f, 0.f, 0.f};

    int cstage = t >> 3;          // 0..31
    int nstage = (t & 7) * 8;     // 0..56

    for (int kk = 0; kk < 8; ++kk) {
        int c0 = kk * 32;
        // stage X[c0..c0+31][n0..n0+63] fp32 into LDS (coalesced)
        {
            const float* src = X + (size_t)(c0 + cstage) * NN + n0 + nstage;
            float4 a0 = ((const float4*)src)[0];
            float4 a1 = ((const float4*)src)[1];
            float2* dp = (float2*)&Xs[cstage * 66 + nstage];
            dp[0] = make_float2(a0.x, a0.y);
            dp[1] = make_float2(a0.z, a0.w);
            dp[2] = make_float2(a1.x, a1.y);
            dp[3] = make_float2(a1.z, a1.w);
        }
        __syncthreads();
        // A fragment: W rows d (row = li), k = c contiguous -> direct global
        const float* wr = W + (size_t)(d0 + wv * 16 + li) * CC + c0 + g * 8;
        float wvv[8];
        *(float4*)&wvv[0] = ((const float4*)wr)[0];
        *(float4*)&wvv[4] = ((const float4*)wr)[1];
        bf16x8 ah, al;
        split8(wvv, ah, al);
#pragma unroll
        for (int nf = 0; nf < 4; ++nf) {
            float bvv[8];
#pragma unroll
            for (int j = 0; j < 8; ++j) bvv[j] = Xs[(g * 8 + j) * 66 + nf * 16 + li];
            bf16x8 bh, bl;
            split8(bvv, bh, bl);
            acc[nf] = MFMA16(ah, bh, acc[nf]);
            acc[nf] = MFMA16(ah, bl, acc[nf]);
            acc[nf] = MFMA16(al, bh, acc[nf]);
        }
        __syncthreads();
    }

    // epilogue: T[d][n] in acc; D col = n = li, row d = g*4+r (m89 layout)
    if (proj == 2) {
        // V: store directly d-major [B][D][N]
#pragma unroll
        for (int r = 0; r < 4; ++r) {
            int d = d0 + wv * 16 + g * 4 + r;
            float bs = bias[d];
#pragma unroll
            for (int nf = 0; nf < 4; ++nf) {
                int n = n0 + nf * 16 + li;
                float v = acc[nf][r] + bs;
                uint32_t h = bf16rne(v);
                uint32_t l2 = bf16rne(v - bf16tof(h));
                size_t o = (size_t)(b * DD + d) * NN + n;
                Vh[o] = (uint16_t)h;
                Vl[o] = (uint16_t)l2;
            }
        }
    } else {
        // Q/K: add pe, (scale for Q), transpose through LDS, store [B][N][D]
#pragma unroll
        for (int r = 0; r < 4; ++r) {
            int d = d0 + wv * 16 + g * 4 + r;
            float bs = bias[d];
            int jj = d & 63;
            float inv = 1.0f / powf(10000.0f, (float)jj * 0.015625f);
#pragma unroll
            for (int nf = 0; nf < 4; ++nf) {
                int n = n0 + nf * 16 + li;
                float v = acc[nf][r] + bs;
                float pos = (d < 128) ? (float)(n & 63) : (float)(n >> 6);
                float ar = pos * inv;
                v += (d & 64) ? cosf(ar) : sinf(ar);
                if (proj == 0) v *= 0.0625f;  // fold softmax scale into Q
                Bz[(nf * 16 + li) * 68 + wv * 16 + g * 4 + r] = v;
            }
        }
        __syncthreads();
        {
            int nl = t >> 2;
            int dk = (t & 3) * 16;
            float vv[16];
#pragma unroll
            for (int q = 0; q < 4; ++q)
                *(float4*)&vv[q * 4] = *(const float4*)&Bz[nl * 68 + dk + q * 4];
            uint32_t h8[8], l8[8];
#pragma unroll
            for (int w = 0; w < 8; ++w) {
                float x = vv[2 * w], y = vv[2 * w + 1];
                uint32_t hx = bf16rne(x), hy = bf16rne(y);
                uint32_t lx = bf16rne(x - bf16tof(hx)), ly = bf16rne(y - bf16tof(hy));
                h8[w] = hx | (hy << 16);
                l8[w] = lx | (ly << 16);
            }
            uint16_t* Ph = (proj == 0) ? Qh : Kh;
            uint16_t* Pl = (proj == 0) ? Ql : Kl;
            size_t o = (size_t)(b * NN + n0 + nl) * DD + d0 + dk;
            u32x4 w0 = {h8[0], h8[1], h8[2], h8[3]};
            u32x4 w1 = {h8[4], h8[5], h8[6], h8[7]};
            u32x4 x0 = {l8[0], l8[1], l8[2], l8[3]};
            u32x4 x1 = {l8[4], l8[5], l8[6], l8[7]};
            ((u32x4*)(Ph + o))[0] = w0;
            ((u32x4*)(Ph + o))[1] = w1;
            ((u32x4*)(Pl + o))[0] = x0;
            ((u32x4*)(Pl + o))[1] = x1;
        }
    }
}

// ---------------------------------------------------------------------------
// Kernel 2: flash attention (swapped QK^T) + fused output projection.
// grid = 256 (XCD-swizzled), 256 threads (4 waves x 16 q-rows), KVBLK=32,
// dynamic LDS = 128 KiB (two 64KB buffers: Khi|Klo|Vhi|Vlo of 16KB each).
// K tile [32 m][256 d] row-major, 16B-chunk swizzle: phys = c ^ (m&7)
// V tile [256 d][32 m] d-major,   16B-chunk swizzle: phys = c ^ ((d^(d>>2))&3)
// Swizzle applied on the per-lane *global source* address (global_load_lds
// writes linearly), and re-applied on the LDS read side.
// ---------------------------------------------------------------------------
__global__ __launch_bounds__(256, 1) void attn_kernel(
    const uint16_t* __restrict__ Qh, const uint16_t* __restrict__ Ql,
    const uint16_t* __restrict__ Kh, const uint16_t* __restrict__ Kl,
    const uint16_t* __restrict__ Vh, const uint16_t* __restrict__ Vl,
    const float* __restrict__ Wo, const float* __restrict__ bo,
    float* __restrict__ Out) {
    extern __shared__ char smem[];

    int t = threadIdx.x;
    int lane = t & 63, wv = t >> 6;
    int g = lane >> 4, li = lane & 15;

    // XCD swizzle: 32 consecutive tiles per XCD -> each XCD sees one batch's K/V
    int orig = ((blockIdx.x & 7) << 5) + (blockIdx.x >> 3);
    int b = orig >> 6;
    int nt = orig & 63;
    int n0 = nt * 64;

    // ---- Q fragments in registers (B-operand layout: col n = li, k contiguous)
    bf16x8 qh[8], ql[8];
    {
        size_t qrow = (size_t)(b * NN + n0 + wv * 16 + li) * DD;
#pragma unroll
        for (int kf = 0; kf < 8; ++kf) {
            qh[kf] = __builtin_bit_cast(bf16x8, *(const u32x4*)(Qh + qrow + kf * 32 + g * 8));
            ql[kf] = __builtin_bit_cast(bf16x8, *(const u32x4*)(Ql + qrow + kf * 32 + g * 8));
        }
    }

    // ---- staging setup: wave 0:Khi 1:Klo 2:Vhi 3:Vlo. 16 x 1KB loads each.
    const uint16_t* splane;
    uint32_t dstbase, adv;
    uint32_t soff[16];
    if (wv < 2) {
        splane = (wv ? Kl : Kh) + (size_t)b * NN * DD;
        dstbase = (uint32_t)wv * 16384u;
        adv = 32 * 256;  // elements per KV step
#pragma unroll
        for (int i = 0; i < 16; ++i) {
            int row = 2 * i + (lane >> 5);
            int clog = (lane & 31) ^ (row & 7);
            soff[i] = (uint32_t)(row * 256 + clog * 8);
        }
    } else {
        splane = (wv == 3 ? Vl : Vh) + (size_t)b * DD * NN;
        dstbase = 32768u + (uint32_t)(wv - 2) * 16384u;
        adv = 32;
#pragma unroll
        for (int i = 0; i < 16; ++i) {
            int row = 16 * i + (lane >> 2);
            int clog = (lane ^ (lane >> 2) ^ (lane >> 4)) & 3;
            soff[i] = (uint32_t)(row * 4096 + clog * 8);
        }
    }

    // LDS read offsets (swizzled)
    uint32_t koff[8];
#pragma unroll
    for (int kf = 0; kf < 8; ++kf) koff[kf] = 16u * (uint32_t)((kf * 4 + g) ^ (li & 7));
    uint32_t voff = (uint32_t)(li * 64 + 16 * (g ^ ((li ^ (li >> 2)) & 3)));

    f32x4 acc[16];  // O^T accumulator: col n = li, row d = df*16 + g*4 + r
#pragma unroll
    for (int i = 0; i < 16; ++i) acc[i] = (f32x4){0.f, 0.f, 0.f, 0.f};
    float mrun = -__builtin_inff();
    float lrun = 0.f;

#define STAGE(tt, sb)                                                                    \
    do {                                                                                 \
        uint32_t mo = (uint32_t)(tt)*adv;                                                \
        char* db = smem + (sb)*65536 + dstbase;                                          \
        _Pragma("unroll") for (int i = 0; i < 16; ++i) {                                 \
            __builtin_amdgcn_global_load_lds(                                            \
                (const __attribute__((address_space(1))) unsigned int*)(splane +         \
                                                                        soff[i] + mo),   \
                (__attribute__((address_space(3))) unsigned int*)(db + i * 1024), 16, 0, \
                0);                                                                      \
        }                                                                                \
    } while (0)

    STAGE(0, 0);
    __syncthreads();

#pragma unroll 1
    for (int tt = 0; tt < 128; ++tt) {
        uint32_t sbase = (tt & 1) ? 65536u : 0u;
        if (tt < 127) STAGE(tt + 1, (tt + 1) & 1);

        // ---- QK: S^T = K*Q  (A = K rows m, B = Q cols n); 3-term split
        f32x4 st0 = {0.f, 0.f, 0.f, 0.f}, st1 = {0.f, 0.f, 0.f, 0.f};
#pragma unroll
        for (int kf = 0; kf < 8; ++kf) {
            const char* kb = smem + sbase + (uint32_t)li * 512 + koff[kf];
            bf16x8 kh0 = ldsld8(kb);
            bf16x8 kh1 = ldsld8(kb + 8192);
            bf16x8 kl0 = ldsld8(kb + 16384);
            bf16x8 kl1 = ldsld8(kb + 8192 + 16384);
            st0 = MFMA16(kh0, qh[kf], st0);
            st1 = MFMA16(kh1, qh[kf], st1);
            st0 = MFMA16(kh0, ql[kf], st0);
            st1 = MFMA16(kh1, ql[kf], st1);
            st0 = MFMA16(kl0, qh[kf], st0);
            st1 = MFMA16(kl1, qh[kf], st1);
        }

        // ---- online softmax; lane holds 8 logits of q-row n=li (m = mf*16+g*4+r)
        float sv[8];
        sv[0] = st0[0]; sv[1] = st0[1]; sv[2] = st0[2]; sv[3] = st0[3];
        sv[4] = st1[0]; sv[5] = st1[1]; sv[6] = st1[2]; sv[7] = st1[3];
        float pm = sv[0];
#pragma unroll
        for (int j = 1; j < 8; ++j) pm = fmaxf(pm, sv[j]);
        pm = fmaxf(pm, __shfl_xor(pm, 16));
        pm = fmaxf(pm, __shfl_xor(pm, 32));
        if (__any(pm > mrun)) {
            float mnew = fmaxf(mrun, pm);
            float fac = __expf(mrun - mnew);
            lrun *= fac;
#pragma unroll
            for (int i = 0; i < 16; ++i) {
                acc[i][0] *= fac; acc[i][1] *= fac;
                acc[i][2] *= fac; acc[i][3] *= fac;
            }
            mrun = mnew;
        }
        float ps = 0.f;
        uint32_t pq[8];
#pragma unroll
        for (int j = 0; j < 8; ++j) {
            float p = __expf(sv[j] - mrun);
            ps += p;
            uint32_t h = bf16rne(p);
            uint32_t l2 = bf16rne(p - bf16tof(h));
            pq[j] = h | (l2 << 16);
        }
        ps += __shfl_xor(ps, 16);
        ps += __shfl_xor(ps, 32);
        lrun += ps;

        // ---- redistribute P^T into PV B-fragment (k = m = 8g+j):
        // element j from lane li+16*((2g+(j>>2))&3), reg (mf=g>>1, r=j&3)
        int s0 = li + 16 * ((2 * g) & 3);
        int s1 = li + 16 * ((2 * g + 1) & 3);
        uint32_t e[8];
#pragma unroll
        for (int r = 0; r < 4; ++r) {
            uint32_t a0 = (uint32_t)__shfl((int)pq[r], s0);
            uint32_t a1 = (uint32_t)__shfl((int)pq[4 + r], s0);
            uint32_t b0 = (uint32_t)__shfl((int)pq[r], s1);
            uint32_t b1 = (uint32_t)__shfl((int)pq[4 + r], s1);
            e[r] = (g < 2) ? a0 : a1;
            e[4 + r] = (g < 2) ? b0 : b1;
        }
        u32x4 bhw, blw;
#pragma unroll
        for (int w = 0; w < 4; ++w) {
            uint32_t x = e[2 * w], y = e[2 * w + 1];
            bhw[w] = (x & 0xffffu) | (y << 16);
            blw[w] = (x >> 16) | (y & 0xffff0000u);
        }
        bf16x8 pbh = __builtin_bit_cast(bf16x8, bhw);
        bf16x8 pbl = __builtin_bit_cast(bf16x8, blw);

        // ---- PV: O^T += V^T * P^T  (A = V^T rows d, B = P^T cols n)
#pragma unroll
        for (int df = 0; df < 16; ++df) {
            const char* vb = smem + sbase + 32768u + (uint32_t)df * 1024 + voff;
            bf16x8 vh = ldsld8(vb);
            bf16x8 vl = ldsld8(vb + 16384);
            acc[df] = MFMA16(vh, pbh, acc[df]);
            acc[df] = MFMA16(vh, pbl, acc[df]);
            acc[df] = MFMA16(vl, pbh, acc[df]);
        }
        __syncthreads();
    }
#undef STAGE

    // ---- normalize and bounce O^T -> lds_z [64 n][260 d] fp32
    float rl = 1.0f / lrun;
    float* z = (float*)smem;
#pragma unroll
    for (int df = 0; df < 16; ++df) {
#pragma unroll
        for (int r = 0; r < 4; ++r)
            z[(wv * 16 + li) * 260 + df * 16 + g * 4 + r] = acc[df][r] * rl;
    }
    __syncthreads();

    // ---- fused output projection: out[cs][n-tile] = Wo * Z^T + bo
    f32x4 oc[4][4];
#pragma unroll
    for (int i = 0; i < 4; ++i)
#pragma unroll
        for (int j = 0; j < 4; ++j) oc[i][j] = (f32x4){0.f, 0.f, 0.f, 0.f};
    int cs0 = wv * 64;
#pragma unroll 1
    for (int kf = 0; kf < 8; ++kf) {
        bf16x8 zh[4], zl[4];
#pragma unroll
        for (int nf = 0; nf < 4; ++nf) {
            float bvv[8];
            *(float4*)&bvv[0] = *(const float4*)&z[(nf * 16 + li) * 260 + kf * 32 + g * 8];
            *(float4*)&bvv[4] =
                *(const float4*)&z[(nf * 16 + li) * 260 + kf * 32 + g * 8 + 4];
            split8(bvv, zh[nf], zl[nf]);
        }
#pragma unroll
        for (int csf = 0; csf < 4; ++csf) {
            const float* wr = Wo + (size_t)(cs0 + csf * 16 + li) * DD + kf * 32 + g * 8;
            float wvv[8];
            *(float4*)&wvv[0] = ((const float4*)wr)[0];
            *(float4*)&wvv[4] = ((const float4*)wr)[1];
            bf16x8 wh, wl;
            split8(wvv, wh, wl);
#pragma unroll
            for (int nf = 0; nf < 4; ++nf) {
                oc[csf][nf] = MFMA16(wh, zh[nf], oc[csf][nf]);
                oc[csf][nf] = MFMA16(wh, zl[nf], oc[csf][nf]);
                oc[csf][nf] = MFMA16(wl, zh[nf], oc[csf][nf]);
            }
        }
    }
#pragma unroll
    for (int csf = 0; csf < 4; ++csf) {
#pragma unroll
        for (int r = 0; r < 4; ++r) {
            int cs = cs0 + csf * 16 + g * 4 + r;
            float bb = bo[cs];
#pragma unroll
            for (int nf = 0; nf < 4; ++nf)
                Out[(size_t)(b * 256 + cs) * NN + n0 + nf * 16 + li] =
                    oc[csf][nf][r] + bb;
        }
    }
}

// ---------------------------------------------------------------------------
extern "C" void kernel_launch(void* const* d_in, const int* in_sizes, int n_in,
                              void* d_out, int out_size, void* d_ws, size_t ws_size,
                              hipStream_t stream) {
    (void)in_sizes; (void)n_in; (void)out_size; (void)ws_size;
    const float* Y = (const float*)d_in[0];
    const float* S = (const float*)d_in[1];
    const float* Wq = (const float*)d_in[2];
    const float* bq = (const float*)d_in[3];
    const float* Wk = (const float*)d_in[4];
    const float* bk = (const float*)d_in[5];
    const float* Wv = (const float*)d_in[6];
    const float* bv = (const float*)d_in[7];
    const float* Wo = (const float*)d_in[8];
    const float* bo = (const float*)d_in[9];
    float* Out = (float*)d_out;

    uint16_t* ws = (uint16_t*)d_ws;
    uint16_t* Qh = ws + 0 * (size_t)PS;
    uint16_t* Ql = ws + 1 * (size_t)PS;
    uint16_t* Kh = ws + 2 * (size_t)PS;
    uint16_t* Kl = ws + 3 * (size_t)PS;
    uint16_t* Vh = ws + 4 * (size_t)PS;
    uint16_t* Vl = ws + 5 * (size_t)PS;

    (void)hipFuncSetAttribute((const void*)attn_kernel,
                              hipFuncAttributeMaxDynamicSharedMemorySize, 131072);

    proj_kernel<<<3072, 256, 0, stream>>>(Y, S, Wq, bq, Wk, bk, Wv, bv,
                                          Qh, Ql, Kh, Kl, Vh, Vl);
    attn_kernel<<<256, 256, 131072, stream>>>(Qh, Ql, Kh, Kl, Vh, Vl, Wo, bo, Out);
}

// Round 2
// 348.557 us; speedup vs baseline: 1.5103x; 1.5103x over previous
//
#include <hip/hip_runtime.h>
#include <stdint.h>

// ---------------------------------------------------------------------------
// CrossAttention2D on MI355X (gfx950)  — round 2
// B=4, C=D=256, H=W=64, N=4096. fp32 in/out.
// fp16 single-plane K/V streams (hi/lo splits only where LDS-free: P, X, Wo, Z),
// flash attention with swapped QK^T, 64KB double-buffered LDS staging via
// global_load_lds with source-side XOR chunk swizzle, fused output projection.
// ---------------------------------------------------------------------------

#define NB 4
#define CC 256
#define DD 256
#define NN 4096
#define PS (NB * NN * DD)   // elements per fp16 plane (4,194,304)

typedef float f32x4 __attribute__((ext_vector_type(4)));
typedef unsigned int u32x4 __attribute__((ext_vector_type(4)));
typedef _Float16 f16x8 __attribute__((ext_vector_type(8)));

#define MFMAH(a, b, c) __builtin_amdgcn_mfma_f32_16x16x32_f16((a), (b), (c), 0, 0, 0)

__device__ __forceinline__ uint16_t h2u(_Float16 h) {
    return __builtin_bit_cast(unsigned short, h);
}
__device__ __forceinline__ uint32_t packh(_Float16 a, _Float16 b) {
    return (uint32_t)h2u(a) | ((uint32_t)h2u(b) << 16);
}
// pack float -> (hi fp16 | lo fp16<<16)
__device__ __forceinline__ uint32_t f16hl(float x) {
    _Float16 h = (_Float16)x;
    _Float16 l = (_Float16)(x - (float)h);
    return packh(h, l);
}
__device__ __forceinline__ f16x8 ldsh8(const void* p) {
    return __builtin_bit_cast(f16x8, *(const u32x4*)p);
}
// split 8 fp32 -> hi/lo f16x8
__device__ __forceinline__ void split8h(const float* v, f16x8& hi, f16x8& lo) {
#pragma unroll
    for (int j = 0; j < 8; ++j) {
        _Float16 h = (_Float16)v[j];
        hi[j] = h;
        lo[j] = (_Float16)(v[j] - (float)h);
    }
}

// ---------------------------------------------------------------------------
// Kernel 1: QKV projections + bias + positional encoding -> fp16 planes
//   proj 0: Q = (Wq*Y + bq + pe) * 1/16   -> Qp [B][N][D]
//   proj 1: K =  Wk*S + bk + pe           -> Kp [B][N][D]
//   proj 2: V =  Wv*S + bv                -> Vp [B][D][N]  (d-major)
// grid = 3*4*4*64 = 3072 blocks of 256 threads; 64x64 output tile each.
// X staged TRANSPOSED in LDS as fp16 hi/lo ([n][c], XOR chunk swizzle) so
// B-fragments are single ds_read_b128.
// ---------------------------------------------------------------------------
__global__ __launch_bounds__(256) void proj_kernel(
    const float* __restrict__ Y, const float* __restrict__ S,
    const float* __restrict__ Wq, const float* __restrict__ bq,
    const float* __restrict__ Wk, const float* __restrict__ bk,
    const float* __restrict__ Wv, const float* __restrict__ bv,
    uint16_t* __restrict__ Qp, uint16_t* __restrict__ Kp,
    uint16_t* __restrict__ Vp) {
    __shared__ char XsH[64 * 64];   // [n=64][c=32] fp16 hi, 64B rows
    __shared__ char XsL[64 * 64];   // lo plane
    __shared__ float Bz[64 * 68];   // transpose bounce [n=64][d=64] pad->68

    int bi = blockIdx.x;
    int proj = bi >> 10;
    int rem = bi & 1023;
    int b = rem >> 8;
    int dt = (rem >> 6) & 3;
    int nt = rem & 63;
    int d0 = dt * 64, n0 = nt * 64;

    int t = threadIdx.x;
    int lane = t & 63, wv = t >> 6;
    int g = lane >> 4, li = lane & 15;

    const float* X = (proj == 0 ? Y : S) + (size_t)b * CC * NN;
    const float* W = proj == 0 ? Wq : (proj == 1 ? Wk : Wv);
    const float* bias = proj == 0 ? bq : (proj == 1 ? bk : bv);

    f32x4 acc[4];
#pragma unroll
    for (int i = 0; i < 4; ++i) acc[i] = (f32x4){0.f, 0.f, 0.f, 0.f};

    int nloc = t & 63;            // staging row (n-local)
    int cq = t >> 6;              // staging c-chunk (8 c's)
    uint32_t spch = (uint32_t)(cq ^ ((nloc >> 1) & 3));  // swizzled phys chunk
    uint32_t rpch = (uint32_t)(g ^ ((li >> 1) & 3));     // read phys chunk

    for (int kk = 0; kk < 8; ++kk) {
        int c0 = kk * 32;
        // stage X[c0+cq*8 .. +7][n0+nloc] transposed -> Xs[n][c] fp16 hi/lo
        {
            const float* xp = X + (size_t)(c0 + cq * 8) * NN + n0 + nloc;
            float xv[8];
#pragma unroll
            for (int j = 0; j < 8; ++j) xv[j] = xp[(size_t)j * NN];
            u32x4 hw, lw;
#pragma unroll
            for (int w = 0; w < 4; ++w) {
                float x = xv[2 * w], y = xv[2 * w + 1];
                _Float16 hx = (_Float16)x, hy = (_Float16)y;
                hw[w] = packh(hx, hy);
                lw[w] = packh((_Float16)(x - (float)hx), (_Float16)(y - (float)hy));
            }
            *(u32x4*)(XsH + nloc * 64 + spch * 16) = hw;
            *(u32x4*)(XsL + nloc * 64 + spch * 16) = lw;
        }
        __syncthreads();
        // A fragment: W row d = d0+wv*16+li, k = c0+g*8.. (hi/lo in regs)
        const float* wr = W + (size_t)(d0 + wv * 16 + li) * CC + c0 + g * 8;
        float wvv[8];
        *(float4*)&wvv[0] = ((const float4*)wr)[0];
        *(float4*)&wvv[4] = ((const float4*)wr)[1];
        f16x8 wh, wl;
        split8h(wvv, wh, wl);
#pragma unroll
        for (int nf = 0; nf < 4; ++nf) {
            const char* bp = XsH + (nf * 16 + li) * 64 + rpch * 16;
            f16x8 xh = ldsh8(bp);
            f16x8 xl = ldsh8(XsL + (nf * 16 + li) * 64 + rpch * 16);
            acc[nf] = MFMAH(wh, xh, acc[nf]);
            acc[nf] = MFMAH(wh, xl, acc[nf]);
            acc[nf] = MFMAH(wl, xh, acc[nf]);
        }
        __syncthreads();
    }

    // epilogue: acc holds T[d][n]; col n = li, row d = g*4+r
    if (proj == 2) {
        // V: store d-major [B][D][N] fp16
#pragma unroll
        for (int r = 0; r < 4; ++r) {
            int d = d0 + wv * 16 + g * 4 + r;
            float bs = bias[d];
#pragma unroll
            for (int nf = 0; nf < 4; ++nf) {
                int n = n0 + nf * 16 + li;
                float v = acc[nf][r] + bs;
                Vp[(size_t)(b * DD + d) * NN + n] = h2u((_Float16)v);
            }
        }
    } else {
        // Q/K: add pe, (scale Q), transpose through LDS, store [B][N][D] fp16
#pragma unroll
        for (int r = 0; r < 4; ++r) {
            int d = d0 + wv * 16 + g * 4 + r;
            float bs = bias[d];
            int jj = d & 63;
            float inv = exp2f((float)jj * -0.20762050594f);  // 10000^(-jj/64)
#pragma unroll
            for (int nf = 0; nf < 4; ++nf) {
                int n = n0 + nf * 16 + li;
                float v = acc[nf][r] + bs;
                float pos = (d < 128) ? (float)(n & 63) : (float)(n >> 6);
                float ar = pos * inv;
                v += (d & 64) ? cosf(ar) : sinf(ar);
                if (proj == 0) v *= 0.0625f;  // fold softmax scale into Q
                Bz[(nf * 16 + li) * 68 + wv * 16 + g * 4 + r] = v;
            }
        }
        __syncthreads();
        {
            int nl = t >> 2;
            int dk = (t & 3) * 16;
            float vv[16];
#pragma unroll
            for (int q = 0; q < 4; ++q)
                *(float4*)&vv[q * 4] = *(const float4*)&Bz[nl * 68 + dk + q * 4];
            u32x4 w0, w1;
#pragma unroll
            for (int w = 0; w < 4; ++w)
                w0[w] = packh((_Float16)vv[2 * w], (_Float16)vv[2 * w + 1]);
#pragma unroll
            for (int w = 0; w < 4; ++w)
                w1[w] = packh((_Float16)vv[8 + 2 * w], (_Float16)vv[9 + 2 * w]);
            uint16_t* Ph = (proj == 0) ? Qp : Kp;
            size_t o = (size_t)(b * NN + n0 + nl) * DD + d0 + dk;
            ((u32x4*)(Ph + o))[0] = w0;
            ((u32x4*)(Ph + o))[1] = w1;
        }
    }
}

// ---------------------------------------------------------------------------
// Kernel 2: flash attention (swapped QK^T) + fused output projection.
// grid = 256 (XCD-swizzled), 256 threads (4 waves x 16 q-rows), KVBLK=32,
// dynamic LDS = 64 KiB (two 32KB buffers: K 16KB | V 16KB).
// K tile [32 m][256 d] fp16, 16B-chunk swizzle: phys = c ^ (m&7)
// V tile [256 d][32 m] fp16, 16B-chunk swizzle: phys = c ^ ((d^(d>>2))&3)
// Swizzle applied on the per-lane *global source* address (global_load_lds
// writes linearly), and re-applied on the LDS read side.
// P kept hi/lo fp16 in registers (2-term PV, no LDS cost).
// ---------------------------------------------------------------------------
__global__ __launch_bounds__(256, 1) void attn_kernel(
    const uint16_t* __restrict__ Qp, const uint16_t* __restrict__ Kp,
    const uint16_t* __restrict__ Vp,
    const float* __restrict__ Wo, const float* __restrict__ bo,
    float* __restrict__ Out) {
    extern __shared__ char smem[];

    int t = threadIdx.x;
    int lane = t & 63, wv = t >> 6;
    int g = lane >> 4, li = lane & 15;

    // XCD swizzle: 32 consecutive tiles per XCD -> each XCD sees one batch's K/V
    int orig = ((blockIdx.x & 7) << 5) + (blockIdx.x >> 3);
    int b = orig >> 6;
    int nt = orig & 63;
    int n0 = nt * 64;

    // ---- Q fragments in registers (B-operand: col n = li, k contiguous g*8)
    f16x8 qh[8];
    {
        size_t qrow = (size_t)(b * NN + n0 + wv * 16 + li) * DD;
#pragma unroll
        for (int kf = 0; kf < 8; ++kf)
            qh[kf] = __builtin_bit_cast(f16x8, *(const u32x4*)(Qp + qrow + kf * 32 + g * 8));
    }

    // ---- staging: wave0: K rows 0-15, wave1: K rows 16-31,
    //               wave2: V d 0-127,  wave3: V d 128-255.  8 x 1KB loads each.
    const uint16_t* splane;
    uint32_t dstbase, adv;
    uint32_t soff[8];
    if (wv < 2) {
        splane = Kp + (size_t)b * NN * DD + (wv ? 16 * 256 : 0);
        dstbase = (uint32_t)wv * 8192u;
        adv = 32 * 256;  // elements per KV step
#pragma unroll
        for (int i = 0; i < 8; ++i) {
            int row = 2 * i + (lane >> 5);
            int clog = (lane & 31) ^ (row & 7);
            soff[i] = (uint32_t)(row * 256 + clog * 8);
        }
    } else {
        splane = Vp + (size_t)b * DD * NN + (wv == 3 ? 128 * 4096 : 0);
        dstbase = 16384u + (uint32_t)(wv - 2) * 8192u;
        adv = 32;
#pragma unroll
        for (int i = 0; i < 8; ++i) {
            int row = 16 * i + (lane >> 2);
            int clog = (lane ^ (lane >> 2) ^ (lane >> 4)) & 3;
            soff[i] = (uint32_t)(row * 4096 + clog * 8);
        }
    }

    // LDS read offsets (swizzled)
    uint32_t koff[8];
#pragma unroll
    for (int kf = 0; kf < 8; ++kf) koff[kf] = 16u * (uint32_t)((kf * 4 + g) ^ (li & 7));
    uint32_t voff = (uint32_t)(li * 64 + 16 * (g ^ ((li ^ (li >> 2)) & 3)));

    f32x4 acc[16];  // O^T: col n = li, row d = df*16 + g*4 + r
#pragma unroll
    for (int i = 0; i < 16; ++i) acc[i] = (f32x4){0.f, 0.f, 0.f, 0.f};
    float mrun = -__builtin_inff();
    float lrun = 0.f;

#define STAGE(tt, sb)                                                                   \
    do {                                                                                \
        uint32_t mo = (uint32_t)(tt)*adv;                                               \
        char* db = smem + (sb)*32768 + dstbase;                                         \
        _Pragma("unroll") for (int i = 0; i < 8; ++i) {                                 \
            __builtin_amdgcn_global_load_lds(                                           \
                (const __attribute__((address_space(1))) unsigned int*)(splane +        \
                                                                        soff[i] + mo),  \
                (__attribute__((address_space(3))) unsigned int*)(db + i * 1024), 16, 0,\
                0);                                                                     \
        }                                                                               \
    } while (0)

    STAGE(0, 0);
    __syncthreads();

#pragma unroll 1
    for (int tt = 0; tt < 128; ++tt) {
        uint32_t sbase = (tt & 1) ? 32768u : 0u;
        if (tt < 127) STAGE(tt + 1, (tt + 1) & 1);

        // ---- QK: S^T = K*Q  (A = K rows m, B = Q cols n)
        f32x4 st0 = {0.f, 0.f, 0.f, 0.f}, st1 = {0.f, 0.f, 0.f, 0.f};
        __builtin_amdgcn_s_setprio(1);
#pragma unroll
        for (int kf = 0; kf < 8; ++kf) {
            const char* kb = smem + sbase + (uint32_t)li * 512 + koff[kf];
            f16x8 k0 = ldsh8(kb);
            f16x8 k1 = ldsh8(kb + 8192);
            st0 = MFMAH(k0, qh[kf], st0);
            st1 = MFMAH(k1, qh[kf], st1);
        }
        __builtin_amdgcn_s_setprio(0);

        // ---- online softmax; lane holds 8 logits of q-row n=li (m = mf*16+g*4+r)
        float sv[8];
        sv[0] = st0[0]; sv[1] = st0[1]; sv[2] = st0[2]; sv[3] = st0[3];
        sv[4] = st1[0]; sv[5] = st1[1]; sv[6] = st1[2]; sv[7] = st1[3];
        float pm = sv[0];
#pragma unroll
        for (int j = 1; j < 8; ++j) pm = fmaxf(pm, sv[j]);
        pm = fmaxf(pm, __shfl_xor(pm, 16));
        pm = fmaxf(pm, __shfl_xor(pm, 32));
        if (__any(pm > mrun + 4.0f)) {   // defer-max (T13): skip small growth
            float mnew = fmaxf(mrun, pm);
            float fac = __expf(mrun - mnew);
            lrun *= fac;
#pragma unroll
            for (int i = 0; i < 16; ++i) {
                acc[i][0] *= fac; acc[i][1] *= fac;
                acc[i][2] *= fac; acc[i][3] *= fac;
            }
            mrun = mnew;
        }
        float ps = 0.f;
        uint32_t pq[8];   // hi fp16 | lo fp16<<16 per P value
#pragma unroll
        for (int j = 0; j < 8; ++j) {
            float p = __expf(sv[j] - mrun);
            ps += p;
            pq[j] = f16hl(p);
        }
        ps += __shfl_xor(ps, 16);
        ps += __shfl_xor(ps, 32);
        lrun += ps;

        // ---- redistribute P^T into PV B-fragment (k = m = 8g+j)
        int s0 = li + 16 * ((2 * g) & 3);
        int s1 = li + 16 * ((2 * g + 1) & 3);
        uint32_t e[8];
#pragma unroll
        for (int r = 0; r < 4; ++r) {
            uint32_t a0 = (uint32_t)__shfl((int)pq[r], s0);
            uint32_t a1 = (uint32_t)__shfl((int)pq[4 + r], s0);
            uint32_t b0 = (uint32_t)__shfl((int)pq[r], s1);
            uint32_t b1 = (uint32_t)__shfl((int)pq[4 + r], s1);
            e[r] = (g < 2) ? a0 : a1;
            e[4 + r] = (g < 2) ? b0 : b1;
        }
        u32x4 bhw, blw;
#pragma unroll
        for (int w = 0; w < 4; ++w) {
            uint32_t x = e[2 * w], y = e[2 * w + 1];
            bhw[w] = (x & 0xffffu) | (y << 16);
            blw[w] = (x >> 16) | (y & 0xffff0000u);
        }
        f16x8 pbh = __builtin_bit_cast(f16x8, bhw);
        f16x8 pbl = __builtin_bit_cast(f16x8, blw);

        // ---- PV: O^T += V^T * P  (A = V^T rows d, B = P cols n); 2-term P
        __builtin_amdgcn_s_setprio(1);
#pragma unroll
        for (int df = 0; df < 16; ++df) {
            const char* vb = smem + sbase + 16384u + (uint32_t)df * 1024 + voff;
            f16x8 vh = ldsh8(vb);
            acc[df] = MFMAH(vh, pbh, acc[df]);
            acc[df] = MFMAH(vh, pbl, acc[df]);
        }
        __builtin_amdgcn_s_setprio(0);
        __syncthreads();
    }
#undef STAGE

    // ---- normalize, bounce O^T -> LDS as fp16 hi/lo [64 n][256 d] swizzled
    float rl = 1.0f / lrun;
    char* zh = smem;            // 32KB
    char* zl = smem + 32768;    // 32KB
    {
        int n = wv * 16 + li;
#pragma unroll
        for (int df = 0; df < 16; ++df) {
#pragma unroll
            for (int rp = 0; rp < 2; ++rp) {
                float a0 = acc[df][2 * rp] * rl, a1 = acc[df][2 * rp + 1] * rl;
                _Float16 h0 = (_Float16)a0, h1 = (_Float16)a1;
                uint32_t whi = packh(h0, h1);
                uint32_t wlo = packh((_Float16)(a0 - (float)h0),
                                     (_Float16)(a1 - (float)h1));
                uint32_t chunk = (uint32_t)((df * 2 + (g >> 1)) ^ (li & 7));
                uint32_t off = (uint32_t)n * 512 + chunk * 16 + (g & 1) * 8 + rp * 4;
                *(uint32_t*)(zh + off) = whi;
                *(uint32_t*)(zl + off) = wlo;
            }
        }
    }
    __syncthreads();

    // ---- fused output projection: out[cs][n-tile] = Wo * Z^T + bo
    f32x4 oc[4][4];
#pragma unroll
    for (int i = 0; i < 4; ++i)
#pragma unroll
        for (int j = 0; j < 4; ++j) oc[i][j] = (f32x4){0.f, 0.f, 0.f, 0.f};
    int cs0 = wv * 64;
#pragma unroll 1
    for (int kf = 0; kf < 8; ++kf) {
        f16x8 zhv[4], zlv[4];
#pragma unroll
        for (int nf = 0; nf < 4; ++nf) {
            uint32_t off = (uint32_t)(nf * 16 + li) * 512 +
                           (uint32_t)((kf * 4 + g) ^ (li & 7)) * 16;
            zhv[nf] = ldsh8(zh + off);
            zlv[nf] = ldsh8(zl + off);
        }
#pragma unroll
        for (int csf = 0; csf < 4; ++csf) {
            const float* wr = Wo + (size_t)(cs0 + csf * 16 + li) * DD + kf * 32 + g * 8;
            float wvv[8];
            *(float4*)&wvv[0] = ((const float4*)wr)[0];
            *(float4*)&wvv[4] = ((const float4*)wr)[1];
            f16x8 wh, wl;
            split8h(wvv, wh, wl);
#pragma unroll
            for (int nf = 0; nf < 4; ++nf) {
                oc[csf][nf] = MFMAH(wh, zhv[nf], oc[csf][nf]);
                oc[csf][nf] = MFMAH(wh, zlv[nf], oc[csf][nf]);
                oc[csf][nf] = MFMAH(wl, zhv[nf], oc[csf][nf]);
            }
        }
    }
#pragma unroll
    for (int csf = 0; csf < 4; ++csf) {
#pragma unroll
        for (int r = 0; r < 4; ++r) {
            int cs = cs0 + csf * 16 + g * 4 + r;
            float bb = bo[cs];
#pragma unroll
            for (int nf = 0; nf < 4; ++nf)
                Out[(size_t)(b * 256 + cs) * NN + n0 + nf * 16 + li] =
                    oc[csf][nf][r] + bb;
        }
    }
}

// ---------------------------------------------------------------------------
extern "C" void kernel_launch(void* const* d_in, const int* in_sizes, int n_in,
                              void* d_out, int out_size, void* d_ws, size_t ws_size,
                              hipStream_t stream) {
    (void)in_sizes; (void)n_in; (void)out_size; (void)ws_size;
    const float* Y = (const float*)d_in[0];
    const float* S = (const float*)d_in[1];
    const float* Wq = (const float*)d_in[2];
    const float* bq = (const float*)d_in[3];
    const float* Wk = (const float*)d_in[4];
    const float* bk = (const float*)d_in[5];
    const float* Wv = (const float*)d_in[6];
    const float* bv = (const float*)d_in[7];
    const float* Wo = (const float*)d_in[8];
    const float* bo = (const float*)d_in[9];
    float* Out = (float*)d_out;

    uint16_t* ws = (uint16_t*)d_ws;
    uint16_t* Qp = ws + 0 * (size_t)PS;
    uint16_t* Kp = ws + 1 * (size_t)PS;
    uint16_t* Vp = ws + 2 * (size_t)PS;

    (void)hipFuncSetAttribute((const void*)attn_kernel,
                              hipFuncAttributeMaxDynamicSharedMemorySize, 65536);

    proj_kernel<<<3072, 256, 0, stream>>>(Y, S, Wq, bq, Wk, bk, Wv, bv, Qp, Kp, Vp);
    attn_kernel<<<256, 256, 65536, stream>>>(Qp, Kp, Vp, Wo, bo, Out);
}